// Round 15
// baseline (17.318 us; speedup 1.0000x reference)
//
#include <hip/hip_runtime.h>

constexpr int NW = 12;
constexpr int BT = 512;   // 1 sample/block; state bits [wid:3][lane:6][j:3]
constexpr int NA = 8;     // amps per thread

typedef float f32x2 __attribute__((ext_vector_type(2)));
typedef float f32x4 __attribute__((ext_vector_type(4)));

// ---- packed FP32 complex math (splat-operand forms HW-validated R8-R14) ----
__device__ __forceinline__ f32x2 pkmul(f32x2 a, f32x2 b) {
    f32x2 d; asm("v_pk_mul_f32 %0, %1, %2" : "=v"(d) : "v"(a), "v"(b)); return d;
}
__device__ __forceinline__ f32x2 pkfma(f32x2 a, f32x2 b, f32x2 c) {
    f32x2 d; asm("v_pk_fma_f32 %0, %1, %2, %3" : "=v"(d) : "v"(a), "v"(b), "v"(c)); return d;
}
__device__ __forceinline__ f32x2 pkfma_swapneg(f32x2 a, f32x2 b, f32x2 c) {
    f32x2 d;
    asm("v_pk_fma_f32 %0, %1, %2, %3 op_sel:[1,0,0] op_sel_hi:[0,1,1] neg_lo:[1,0,0]"
        : "=v"(d) : "v"(a), "v"(b), "v"(c));
    return d;
}
__device__ __forceinline__ f32x2 cmul(f32x2 z, f32x2 ur, f32x2 ui) {
    return pkfma_swapneg(z, ui, pkmul(z, ur));
}
__device__ __forceinline__ f32x2 cmac(f32x2 z, f32x2 ur, f32x2 ui, f32x2 acc) {
    return pkfma_swapneg(z, ui, pkfma(z, ur, acc));
}

// ---- broadcast-operand forms: coefficient stays packed {re,im}; op_sel splats ----
// d = z * c.lo (both halves)
__device__ __forceinline__ f32x2 pkmul_bc0(f32x2 z, f32x2 c) {
    f32x2 d;
    asm("v_pk_mul_f32 %0, %1, %2 op_sel:[0,0] op_sel_hi:[1,0]" : "=v"(d) : "v"(z), "v"(c));
    return d;
}
// d = z * c.lo + acc
__device__ __forceinline__ f32x2 pkfma_bc0(f32x2 z, f32x2 c, f32x2 acc) {
    f32x2 d;
    asm("v_pk_fma_f32 %0, %1, %2, %3 op_sel:[0,0,0] op_sel_hi:[1,0,1]"
        : "=v"(d) : "v"(z), "v"(c), "v"(acc));
    return d;
}
// d.lo = -z.hi*c.hi + acc.lo ; d.hi = z.lo*c.hi + acc.hi
__device__ __forceinline__ f32x2 pkfma_swapneg_bc1(f32x2 z, f32x2 c, f32x2 acc) {
    f32x2 d;
    asm("v_pk_fma_f32 %0, %1, %2, %3 op_sel:[1,1,0] op_sel_hi:[0,1,1] neg_lo:[1,0,0]"
        : "=v"(d) : "v"(z), "v"(c), "v"(acc));
    return d;
}

// complex multiply/mac with packed coefficient c = {re, im}
template<bool FAST>
__device__ __forceinline__ f32x2 cmulb(f32x2 z, f32x2 c) {
    if constexpr (FAST) return pkfma_swapneg_bc1(z, c, pkmul_bc0(z, c));
    else { f32x2 ur = {c.x, c.x}, ui = {c.y, c.y}; return cmul(z, ur, ui); }
}
template<bool FAST>
__device__ __forceinline__ f32x2 cmacb(f32x2 z, f32x2 c, f32x2 acc) {
    if constexpr (FAST) return pkfma_swapneg_bc1(z, c, pkfma_bc0(z, c, acc));
    else { f32x2 ur = {c.x, c.x}, ui = {c.y, c.y}; return cmac(z, ur, ui, acc); }
}

struct St { f32x2 z[NA]; };

// ---- cross-lane (validated R6/R14) ----
template<int CTRL>
__device__ __forceinline__ float dppx(float v) {
    int r = __builtin_amdgcn_update_dpp(0, __builtin_bit_cast(int, v), CTRL, 0xF, 0xF, true);
    return __builtin_bit_cast(float, r);
}
__device__ __forceinline__ float permswap16(float v) {
    int r = __builtin_bit_cast(int, v);
    asm("v_permlane16_swap_b32 %0, %0" : "+v"(r));
    return __builtin_bit_cast(float, r);
}
__device__ __forceinline__ float permswap32(float v) {
    int r = __builtin_bit_cast(int, v);
    asm("v_permlane32_swap_b32 %0, %0" : "+v"(r));
    return __builtin_bit_cast(float, r);
}
template<int M, bool FAST>
__device__ __forceinline__ float lxor(float v, int bp32) {
    if constexpr (M == 1)      { return dppx<0xB1>(v); }
    else if constexpr (M == 2) { return dppx<0x4E>(v); }
    else if constexpr (M == 8) { return dppx<0x128>(v); }
    else if constexpr (M == 4) {
        if constexpr (FAST) return dppx<0x1B>(dppx<0x141>(v));  // xor7 . xor3 = xor4
        else {
            int r = __builtin_amdgcn_ds_swizzle(__builtin_bit_cast(int, v), 0x101F);
            return __builtin_bit_cast(float, r);
        }
    } else if constexpr (M == 16) {
        if constexpr (FAST) return permswap16(v);
        else {
            int r = __builtin_amdgcn_ds_swizzle(__builtin_bit_cast(int, v), 0x401F);
            return __builtin_bit_cast(float, r);
        }
    } else {
        if constexpr (FAST) return permswap32(v);
        else {
            int r = __builtin_amdgcn_ds_bpermute(bp32, __builtin_bit_cast(int, v));
            return __builtin_bit_cast(float, r);
        }
    }
}
template<int M, bool FAST>
__device__ __forceinline__ f32x2 lxor2(f32x2 z, int bp32) {
    f32x2 p; p.x = lxor<M,FAST>(z.x, bp32); p.y = lxor<M,FAST>(z.y, bp32); return p;
}

// ---- Rot gates, packed-coefficient tables ----
// local gate: u2[0]={r00,i00,r01,i01}, u2[1]={r10,i10,r11,i11}  (2 x b128)
template<int LM, bool FAST>
__device__ __forceinline__ void gate_local(St& s, const f32x4* u2) {
    const f32x4 ua = u2[0], ub = u2[1];
    const f32x2 u00 = {ua.x, ua.y}, u01 = {ua.z, ua.w};
    const f32x2 u10 = {ub.x, ub.y}, u11 = {ub.z, ub.w};
    #pragma unroll
    for (int j0 = 0; j0 < NA; ++j0) {
        if (j0 & LM) continue;
        const int j1 = j0 | LM;
        f32x2 z0 = s.z[j0], z1 = s.z[j1];
        s.z[j0] = cmacb<FAST>(z1, u01, cmulb<FAST>(z0, u00));
        s.z[j1] = cmacb<FAST>(z1, u11, cmulb<FAST>(z0, u10));
    }
}
// lane gate: g = {ar,ai,br,bi} pre-selected by lane bit (1 x b128)
template<int M, bool FAST>
__device__ __forceinline__ void gate_lane(St& s, const f32x4* gp, int bp32) {
    const f32x4 g = *gp;
    const f32x2 a = {g.x, g.y}, bb = {g.z, g.w};
    #pragma unroll
    for (int j = 0; j < NA; ++j) {
        f32x2 p = lxor2<M,FAST>(s.z[j], bp32);
        s.z[j] = cmacb<FAST>(p, bb, cmulb<FAST>(s.z[j], a));
    }
}

// ---- transpose: swap 3 wid bits with 3 j bits (one barrier; validated R7) ----
__device__ __forceinline__ void transpose_wl(St& s, int t, int wid, int lane, f32x2* ex) {
    #pragma unroll
    for (int j = 0; j < NA; ++j) ex[(j<<9) | t] = s.z[j];
    __syncthreads();
    #pragma unroll
    for (int j = 0; j < NA; ++j) s.z[j] = ex[(wid<<9) | (j<<6) | lane];
}

// ---- circuit (R11-validated structure; R15 packed tables) ----
// L1 layout: y0..y2=j2,j1,j0 | y3..y8=l5..l0 | y9..y11=w2..w0
// x = M1^-1 y: x0=j2^w0  x1=j1^j2^w0  x2=j0^j1  x3=l5^j0  x4=l4^l5 ... x8=l0^l1
//              x9=w2^l0  x10=w1^w2  x11=w0^w1
template<bool FAST>
__device__ __forceinline__ void circuit(St& s, f32x2* ex,
                                        const f32x4 (*rotl)[2],
                                        const f32x4 (*rotg2)[2],
                                        const f32x2* fac2,
                                        int t, int lane, int wid, int bp32) {
    const int l = lane, W = wid;
    auto ldf = [&](int w, int bit) -> f32x2 { return fac2[(w << 1) | bit]; };
    {
        const int b4  = ((l>>4) ^ (l>>5)) & 1;
        const int b5  = ((l>>3) ^ (l>>4)) & 1;
        const int b6  = ((l>>2) ^ (l>>3)) & 1;
        const int b7  = ((l>>1) ^ (l>>2)) & 1;
        const int b8  = ( l     ^ (l>>1)) & 1;
        const int b9  = ((W>>2) ^  l    ) & 1;
        const int b10 = ((W>>1) ^ (W>>2)) & 1;
        const int b11 = ( W     ^ (W>>1)) & 1;
        f32x2 P = ldf(4, b4);
        P = cmulb<FAST>(P, ldf(5,  b5));
        P = cmulb<FAST>(P, ldf(6,  b6));
        P = cmulb<FAST>(P, ldf(7,  b7));
        P = cmulb<FAST>(P, ldf(8,  b8));
        P = cmulb<FAST>(P, ldf(9,  b9));
        P = cmulb<FAST>(P, ldf(10, b10));
        P = cmulb<FAST>(P, ldf(11, b11));
        const int w0 = W & 1, l5 = (l >> 5) & 1;
        f32x2 v0a = ldf(0, w0),  v0b = ldf(0, w0 ^ 1);   // index j2
        f32x2 v1a = ldf(1, w0),  v1b = ldf(1, w0 ^ 1);   // index j1^j2
        f32x2 v2a = ldf(2, 0),   v2b = ldf(2, 1);        // index j0^j1
        f32x2 v3a = ldf(3, l5),  v3b = ldf(3, l5 ^ 1);   // index j0
        #pragma unroll
        for (int j = 0; j < NA; ++j) {
            const int a0 = (j >> 2) & 1;
            const int a1 = ((j >> 1) ^ (j >> 2)) & 1;
            const int a2 = (j ^ (j >> 1)) & 1;
            const int a3 = j & 1;
            f32x2 z = cmulb<FAST>(P, a0 ? v0b : v0a);    // compile-time selects
            z = cmulb<FAST>(z, a1 ? v1b : v1a);
            z = cmulb<FAST>(z, a2 ? v2b : v2a);
            z = cmulb<FAST>(z, a3 ? v3b : v3a);
            s.z[j] = z;
        }
    }
    // ===== layer 1 Rot sweep (L1) =====
    gate_local<4,FAST>(s, rotl[0]);                    // wire0
    gate_local<2,FAST>(s, rotl[1]);                    // wire1
    gate_local<1,FAST>(s, rotl[2]);                    // wire2
    gate_lane<32,FAST>(s, &rotg2[0][(lane>>5)&1], bp32);  // wire3
    gate_lane<16,FAST>(s, &rotg2[1][(lane>>4)&1], bp32);  // wire4
    gate_lane<8,FAST >(s, &rotg2[2][(lane>>3)&1], bp32);  // wire5
    gate_lane<4,FAST >(s, &rotg2[3][(lane>>2)&1], bp32);  // wire6
    gate_lane<2,FAST >(s, &rotg2[4][(lane>>1)&1], bp32);  // wire7
    gate_lane<1,FAST >(s, &rotg2[5][ lane    &1], bp32);  // wire8
    transpose_wl(s, t, wid, lane, ex);                 // -> L0
    gate_local<4,FAST>(s, rotl[3]);                    // wire9
    gate_local<2,FAST>(s, rotl[4]);                    // wire10
    gate_local<1,FAST>(s, rotl[5]);                    // wire11
}

// cold fallback (never taken when self-check passes) kept out of the hot path
__device__ __attribute__((noinline))
void circuit_fallback(St& s, f32x2* ex, const f32x4 (*rotl)[2], const f32x4 (*rotg2)[2],
                      const f32x2* fac2, int t, int lane, int wid, int bp32) {
    circuit<false>(s, ex, rotl, rotg2, fac2, t, lane, wid, bp32);
}

__global__ __launch_bounds__(BT)
void qnn_kernel(const float* __restrict__ x, const float* __restrict__ var,
                const float* __restrict__ hw, const float* __restrict__ hb,
                float* __restrict__ out)
{
    __shared__ f32x2 ex[NA * BT];                   // 32 KiB
    __shared__ __align__(16) f32x4 rotl[6][2];      // local-gate packed matrices
    __shared__ __align__(16) f32x4 rotg2[6][2];     // lane-gate pre-selected {ar,ai,br,bi}
    __shared__ __align__(8)  f32x2 fac2[24];        // v_w[b] = {re,im}
    __shared__ float wavesum[8];

    const int t    = threadIdx.x;
    const int b    = blockIdx.x;
    const int lane = t & 63;
    const int wid  = t >> 6;
    const int bp32 = (lane ^ 32) << 2;

    // self-check: VALU cross-lane + op_sel broadcast semantics (exact fp32; wave-uniform)
    bool fast_ok;
    {
        float lv = __builtin_bit_cast(float, lane);
        int r16 = __builtin_bit_cast(int, permswap16(lv));
        int r32 = __builtin_bit_cast(int, permswap32(lv));
        int r4  = __builtin_bit_cast(int, dppx<0x1B>(dppx<0x141>(lv)));
        f32x2 zc = {1.0f, 2.0f}, cc = {3.0f, 5.0f}, ac = {0.25f, -0.5f};
        f32x2 r = pkfma_swapneg_bc1(zc, cc, pkfma_bc0(zc, cc, ac));   // cmacb fast form
        bool bc = (r.x == -6.75f) && (r.y == 10.5f);
        fast_ok = __all((r16 == (lane ^ 16)) && (r32 == (lane ^ 32)) &&
                        (r4 == (lane ^ 4)) && bc);
    }

    if (wid == 0 && lane < 12) {
        // layer-1 Rot matrix for wire `lane` (packed {re,im})
        const int w = lane;
        const int g = 12 + w;
        const float phi   = var[g*3+0];
        const float theta = var[g*3+1];
        const float omega = var[g*3+2];
        float st, ct; sincosf(0.5f*theta, &st, &ct);
        float sp, cp; sincosf(-0.5f*(phi+omega), &sp, &cp);
        float sm, cm; sincosf(-0.5f*(phi-omega), &sm, &cm);
        const float v0r =  cp*ct, v0i =  sp*ct;   // u00
        const float v1r = -cm*st, v1i =  sm*st;   // u01
        const float v2r =  cm*st, v2i =  sm*st;   // u10
        const float v3r =  cp*ct, v3i = -sp*ct;   // u11
        // local gates: wires 0,1,2 -> rotl[0..2]; wires 9,10,11 -> rotl[3..5]
        int li = (w < 3) ? w : (w >= 9 ? w - 6 : -1);
        if (li >= 0) {
            rotl[li][0] = f32x4{v0r, v0i, v1r, v1i};
            rotl[li][1] = f32x4{v2r, v2i, v3r, v3i};
        }
        if (w >= 3 && w < 9) {
            rotg2[w-3][0] = f32x4{v0r, v0i, v1r, v1i};  // bit=0: a=u00, b=u01
            rotg2[w-3][1] = f32x4{v3r, v3i, v2r, v2i};  // bit=1: a=u11, b=u10
        }
    } else if (wid == 1 && lane < 12) {
        // v_w = Rot^0_w * RY(x_w)|0>  (layer-0 product factor table, packed)
        const int w = lane;
        const float phi   = var[w*3+0];
        const float theta = var[w*3+1];
        const float omega = var[w*3+2];
        float st, ct; sincosf(0.5f*theta, &st, &ct);
        float sp, cp; sincosf(-0.5f*(phi+omega), &sp, &cp);
        float sm, cm; sincosf(-0.5f*(phi-omega), &sm, &cm);
        float s_, c_; sincosf(0.5f * x[b*NW + w], &s_, &c_);
        const float v0r = cp*ct*c_ - cm*st*s_;
        const float v0i = sp*ct*c_ + sm*st*s_;
        const float v1r = cm*st*c_ + cp*ct*s_;
        const float v1i = sm*st*c_ - sp*ct*s_;
        fac2[w*2+0] = f32x2{v0r, v0i};
        fac2[w*2+1] = f32x2{v1r, v1i};
    }
    __syncthreads();

    St s;
    if (fast_ok) circuit<true>(s, ex, rotl, rotg2, fac2, t, lane, wid, bp32);
    else         circuit_fallback(s, ex, rotl, rotg2, fac2, t, lane, wid, bp32);

    // ---- epilogue: probs -> z(M2 x) -> head (ring r=2 fused; validated R10/R11) ----
    // L0: x0=W2 x1=W1 x2=W0 | x3..x8 = l5..l0 | x9=j2 x10=j1 x11=j0
    float h[NW];
    #pragma unroll
    for (int w = 0; w < NW; ++w) h[w] = hw[w];
    const int W = wid, l = lane;
    const int s2 = ((W >> 2) ^ W) & 1;
    const int s3 = ((W >> 1) ^ (l >> 5)) & 1;
    const int s4 = s2 ^ ((l >> 4) & 1);
    const int s5 = s3 ^ ((l >> 3) & 1);
    const int s6 = s4 ^ ((l >> 2) & 1);
    const int s7 = s5 ^ ((l >> 1) & 1);
    const int s8 = s6 ^ (l & 1);
    const int c0 = (W ^ (l >> 4) ^ (l >> 2) ^ l) & 1;
    const int c10 = c0 ^ ((W >> 2) & 1);
    const int c9 = ((W >> 1) ^ (l >> 5) ^ (l >> 3) ^ (l >> 1)) & 1;
    const int c1 = c9 ^ ((W >> 1) & 1);

    const float base =
        (s2 ? -h[2] : h[2]) + (s3 ? -h[3] : h[3]) + (s4 ? -h[4] : h[4]) +
        (s5 ? -h[5] : h[5]) + (s6 ? -h[6] : h[6]) + (s7 ? -h[7] : h[7]) +
        (s8 ? -h[8] : h[8]);
    const float A  = (c0 ? -h[0] : h[0]) + (c10 ? -h[10] : h[10]);   // * (-1)^j1
    const float B  = (c1 ? -h[1] : h[1]) + (c9  ? -h[11] : h[11]);   // * (-1)^(j2^j0)
    const float Cc = (c9 ? -h[9] : h[9]);                            // * (-1)^j2

    float acc = 0.0f;
    #pragma unroll
    for (int j = 0; j < NA; ++j) {
        const float pr = s.z[j].x*s.z[j].x + s.z[j].y*s.z[j].y;
        float zz = base;
        zz += (j & 2) ? -A : A;
        zz += (j & 4) ? -Cc : Cc;
        zz += (((j >> 2) ^ j) & 1) ? -B : B;
        acc += pr * zz;
    }
    #pragma unroll
    for (int off = 32; off > 0; off >>= 1) acc += __shfl_down(acc, off, 64);
    if (lane == 0) wavesum[wid] = acc;
    __syncthreads();
    if (t == 0) {
        float r = hb[0];
        #pragma unroll
        for (int wv = 0; wv < 8; ++wv) r += wavesum[wv];
        out[b] = r;
    }
}

extern "C" void kernel_launch(void* const* d_in, const int* in_sizes, int n_in,
                              void* d_out, int out_size, void* d_ws, size_t ws_size,
                              hipStream_t stream) {
    const float* x   = (const float*)d_in[0];
    const float* var = (const float*)d_in[1];
    const float* hw  = (const float*)d_in[2];
    const float* hb  = (const float*)d_in[3];
    float* out = (float*)d_out;
    qnn_kernel<<<out_size, BT, 0, stream>>>(x, var, hw, hb, out);
}

// Round 16
// 13.122 us; speedup vs baseline: 1.3198x; 1.3198x over previous
//
#include <hip/hip_runtime.h>

constexpr int NW = 12;
constexpr int BT = 512;   // 1 sample/block; state bits [wid:3][lane:6][j:3]
constexpr int NA = 8;     // amps per thread

typedef float f32x2 __attribute__((ext_vector_type(2)));
typedef float f32x4 __attribute__((ext_vector_type(4)));

// ---- packed FP32 complex math (HW-validated R8-R13) ----
__device__ __forceinline__ f32x2 pkmul(f32x2 a, f32x2 b) {
    f32x2 d; asm("v_pk_mul_f32 %0, %1, %2" : "=v"(d) : "v"(a), "v"(b)); return d;
}
__device__ __forceinline__ f32x2 pkfma(f32x2 a, f32x2 b, f32x2 c) {
    f32x2 d; asm("v_pk_fma_f32 %0, %1, %2, %3" : "=v"(d) : "v"(a), "v"(b), "v"(c)); return d;
}
__device__ __forceinline__ f32x2 pkfma_swapneg(f32x2 a, f32x2 b, f32x2 c) {
    f32x2 d;
    asm("v_pk_fma_f32 %0, %1, %2, %3 op_sel:[1,0,0] op_sel_hi:[0,1,1] neg_lo:[1,0,0]"
        : "=v"(d) : "v"(a), "v"(b), "v"(c));
    return d;
}
__device__ __forceinline__ f32x2 cmul(f32x2 z, f32x2 ur, f32x2 ui) {
    return pkfma_swapneg(z, ui, pkmul(z, ur));
}
__device__ __forceinline__ f32x2 cmac(f32x2 z, f32x2 ur, f32x2 ui, f32x2 acc) {
    return pkfma_swapneg(z, ui, pkfma(z, ur, acc));
}
// packed{re,im} x packed{re,im} complex product
__device__ __forceinline__ f32x2 cpmul(f32x2 a, f32x2 b) {
    return f32x2{a.x*b.x - a.y*b.y, a.x*b.y + a.y*b.x};
}

struct C2p { f32x2 r00,i00,r01,i01,r10,i10,r11,i11; };
struct St  { f32x2 z[NA]; };

// ---- cross-lane ----
template<int CTRL>
__device__ __forceinline__ float dppx(float v) {
    int r = __builtin_amdgcn_update_dpp(0, __builtin_bit_cast(int, v), CTRL, 0xF, 0xF, true);
    return __builtin_bit_cast(float, r);
}
__device__ __forceinline__ float permswap16(float v) {
    int r = __builtin_bit_cast(int, v);
    asm("v_permlane16_swap_b32 %0, %0" : "+v"(r));
    return __builtin_bit_cast(float, r);
}
__device__ __forceinline__ float permswap32(float v) {
    int r = __builtin_bit_cast(int, v);
    asm("v_permlane32_swap_b32 %0, %0" : "+v"(r));
    return __builtin_bit_cast(float, r);
}

// partner across lane-xor M. FAST: VALU-pipe variants for 4/16/32 (self-checked).
template<int M, bool FAST>
__device__ __forceinline__ float lxor(float v, int bp32) {
    if constexpr (M == 1)      { return dppx<0xB1>(v); }     // quad_perm [1,0,3,2]
    else if constexpr (M == 2) { return dppx<0x4E>(v); }     // quad_perm [2,3,0,1]
    else if constexpr (M == 8) { return dppx<0x128>(v); }    // row_ror:8
    else if constexpr (M == 4) {
        if constexpr (FAST) return dppx<0x1B>(dppx<0x141>(v));  // xor7 then xor3 = xor4
        else {
            int r = __builtin_amdgcn_ds_swizzle(__builtin_bit_cast(int, v), 0x101F);
            return __builtin_bit_cast(float, r);
        }
    } else if constexpr (M == 16) {
        if constexpr (FAST) return permswap16(v);
        else {
            int r = __builtin_amdgcn_ds_swizzle(__builtin_bit_cast(int, v), 0x401F);
            return __builtin_bit_cast(float, r);
        }
    } else {
        if constexpr (FAST) return permswap32(v);
        else {
            int r = __builtin_amdgcn_ds_bpermute(bp32, __builtin_bit_cast(int, v));
            return __builtin_bit_cast(float, r);
        }
    }
}
template<int M, bool FAST>
__device__ __forceinline__ f32x2 lxor2(f32x2 z, int bp32) {
    f32x2 p; p.x = lxor<M,FAST>(z.x, bp32); p.y = lxor<M,FAST>(z.y, bp32); return p;
}

// ---- Rot gates ----
template<int LM>
__device__ __forceinline__ void gate_local(St& s, const C2p& u) {
    #pragma unroll
    for (int j0 = 0; j0 < NA; ++j0) {
        if (j0 & LM) continue;
        const int j1 = j0 | LM;
        f32x2 z0 = s.z[j0], z1 = s.z[j1];
        s.z[j0] = cmac(z1, u.r01, u.i01, cmul(z0, u.r00, u.i00));
        s.z[j1] = cmac(z1, u.r11, u.i11, cmul(z0, u.r10, u.i10));
    }
}
// lane gate: coefficients pre-selected by lane bit (4 f32x2: ar,ai,br,bi)
template<int M, bool FAST>
__device__ __forceinline__ void gate_lane(St& s, const f32x2* g, int bp32) {
    f32x2 ar = g[0], ai = g[1], br = g[2], bi = g[3];
    #pragma unroll
    for (int j = 0; j < NA; ++j) {
        f32x2 p = lxor2<M,FAST>(s.z[j], bp32);
        s.z[j] = cmac(p, br, bi, cmul(s.z[j], ar, ai));
    }
}

// ---- transpose: swap 3 wid bits with 3 j bits (one barrier; validated R7) ----
__device__ __forceinline__ void transpose_wl(St& s, int t, int wid, int lane, f32x2* ex) {
    #pragma unroll
    for (int j = 0; j < NA; ++j) ex[(j<<9) | t] = s.z[j];
    __syncthreads();
    #pragma unroll
    for (int j = 0; j < NA; ++j) s.z[j] = ex[(wid<<9) | (j<<6) | lane];
}

// ---- circuit (R11-validated structure) ----
// L1 layout: y0..y2=j2,j1,j0 | y3..y8=l5..l0 | y9..y11=w2..w0
// x = M1^-1 y: x0=j2^w0  x1=j1^j2^w0  x2=j0^j1  x3=l5^j0  x4=l4^l5 ... x8=l0^l1
//              x9=w2^l0  x10=w1^w2  x11=w0^w1
template<bool FAST>
__device__ __forceinline__ void circuit(St& s, f32x2* ex,
                                        const f32x2 (*rotu)[8],
                                        const f32x2 (*rotg)[2][4],
                                        const float (*fac)[4],
                                        int t, int lane, int wid, int bp32) {
    const int l = lane, W = wid;
    auto ldf = [&](int w, int bit) -> f32x4 {
        return *reinterpret_cast<const f32x4*>(fac[(w << 1) | bit]);  // {re,re,im,im}
    };
    {
        const int b4  = ((l>>4) ^ (l>>5)) & 1;
        const int b5  = ((l>>3) ^ (l>>4)) & 1;
        const int b6  = ((l>>2) ^ (l>>3)) & 1;
        const int b7  = ((l>>1) ^ (l>>2)) & 1;
        const int b8  = ( l     ^ (l>>1)) & 1;
        const int b9  = ((W>>2) ^  l    ) & 1;
        const int b10 = ((W>>1) ^ (W>>2)) & 1;
        const int b11 = ( W     ^ (W>>1)) & 1;
        // tree-structured prefix: 3 parallel chains + 2 packed-packed muls
        f32x4 f4 = ldf(4,b4), f5 = ldf(5,b5), f6 = ldf(6,b6), f7 = ldf(7,b7);
        f32x4 f8 = ldf(8,b8), f9 = ldf(9,b9), fA = ldf(10,b10), fB = ldf(11,b11);
        f32x2 cA = cmul(f32x2{f4.x,f4.z}, f32x2{f5.x,f5.y}, f32x2{f5.z,f5.w});
        cA = cmul(cA, f32x2{f6.x,f6.y}, f32x2{f6.z,f6.w});
        f32x2 cB = cmul(f32x2{f7.x,f7.z}, f32x2{f8.x,f8.y}, f32x2{f8.z,f8.w});
        cB = cmul(cB, f32x2{f9.x,f9.y}, f32x2{f9.z,f9.w});
        f32x2 cC = cmul(f32x2{fA.x,fA.z}, f32x2{fB.x,fB.y}, f32x2{fB.z,fB.w});
        f32x2 P = cpmul(cpmul(cA, cB), cC);
        const int w0 = W & 1, l5 = (l >> 5) & 1;
        f32x4 v0a = ldf(0, w0),  v0b = ldf(0, w0 ^ 1);   // index j2
        f32x4 v1a = ldf(1, w0),  v1b = ldf(1, w0 ^ 1);   // index j1^j2
        f32x4 v2a = ldf(2, 0),   v2b = ldf(2, 1);        // index j0^j1
        f32x4 v3a = ldf(3, l5),  v3b = ldf(3, l5 ^ 1);   // index j0
        #pragma unroll
        for (int j = 0; j < NA; ++j) {
            const int a0 = (j >> 2) & 1;
            const int a1 = ((j >> 1) ^ (j >> 2)) & 1;
            const int a2 = (j ^ (j >> 1)) & 1;
            const int a3 = j & 1;
            const f32x4 g0 = a0 ? v0b : v0a;   // compile-time selects
            const f32x4 g1 = a1 ? v1b : v1a;
            const f32x4 g2 = a2 ? v2b : v2a;
            const f32x4 g3 = a3 ? v3b : v3a;
            f32x2 z = cmul(P, f32x2{g0.x,g0.y}, f32x2{g0.z,g0.w});
            z = cmul(z, f32x2{g1.x,g1.y}, f32x2{g1.z,g1.w});
            z = cmul(z, f32x2{g2.x,g2.y}, f32x2{g2.z,g2.w});
            z = cmul(z, f32x2{g3.x,g3.y}, f32x2{g3.z,g3.w});
            s.z[j] = z;
        }
    }
    // ===== layer 1 Rot sweep (L1) =====
    auto ld = [&](int g) -> C2p {
        C2p u;
        u.r00 = rotu[g][0]; u.i00 = rotu[g][1];
        u.r01 = rotu[g][2]; u.i01 = rotu[g][3];
        u.r10 = rotu[g][4]; u.i10 = rotu[g][5];
        u.r11 = rotu[g][6]; u.i11 = rotu[g][7];
        return u;
    };
    { C2p u = ld(0);  gate_local<4>(s, u); }               // wire0
    { C2p u = ld(1);  gate_local<2>(s, u); }               // wire1
    { C2p u = ld(2);  gate_local<1>(s, u); }               // wire2
    gate_lane<32,FAST>(s, rotg[0][(lane>>5)&1], bp32);     // wire3
    gate_lane<16,FAST>(s, rotg[1][(lane>>4)&1], bp32);     // wire4
    gate_lane<8,FAST >(s, rotg[2][(lane>>3)&1], bp32);     // wire5
    gate_lane<4,FAST >(s, rotg[3][(lane>>2)&1], bp32);     // wire6
    gate_lane<2,FAST >(s, rotg[4][(lane>>1)&1], bp32);     // wire7
    gate_lane<1,FAST >(s, rotg[5][ lane    &1], bp32);     // wire8
    transpose_wl(s, t, wid, lane, ex);                     // -> L0
    { C2p u = ld(9);  gate_local<4>(s, u); }               // wire9
    { C2p u = ld(10); gate_local<2>(s, u); }
    { C2p u = ld(11); gate_local<1>(s, u); }
}

__global__ __launch_bounds__(BT)
void qnn_kernel(const float* __restrict__ x, const float* __restrict__ var,
                const float* __restrict__ hw, const float* __restrict__ hb,
                float* __restrict__ out)
{
    __shared__ f32x2 ex[NA * BT];                  // 32 KiB
    __shared__ f32x2 rotu[12][8];                  // layer-1 splat matrices (local gates)
    __shared__ __align__(16) f32x2 rotg[6][2][4];  // lane-gate pre-selected {ar,ai,br,bi}
    __shared__ __align__(16) float fac[24][4];     // v_w[b] = {re,re,im,im}
    __shared__ float wavesum[8];

    const int t    = threadIdx.x;
    const int b    = blockIdx.x;
    const int lane = t & 63;
    const int wid  = t >> 6;
    const int bp32 = (lane ^ 32) << 2;

    // VALU cross-lane semantics self-check (wave-uniform; fallback = validated DS path)
    bool fast_ok;
    {
        float lv = __builtin_bit_cast(float, lane);
        int r16 = __builtin_bit_cast(int, permswap16(lv));
        int r32 = __builtin_bit_cast(int, permswap32(lv));
        int r4  = __builtin_bit_cast(int, dppx<0x1B>(dppx<0x141>(lv)));
        fast_ok = __all((r16 == (lane ^ 16)) && (r32 == (lane ^ 32)) && (r4 == (lane ^ 4)));
    }

    if (wid == 0 && lane < 12) {
        // layer-1 Rot matrix for wire `lane`, splatted (+ lane-gate table for wires 3-8)
        const int w = lane;
        const int g = 12 + w;
        const float phi   = var[g*3+0];
        const float theta = var[g*3+1];
        const float omega = var[g*3+2];
        float st, ct; sincosf(0.5f*theta, &st, &ct);
        float sp, cp; sincosf(-0.5f*(phi+omega), &sp, &cp);
        float sm, cm; sincosf(-0.5f*(phi-omega), &sm, &cm);
        const float v0r =  cp*ct, v0i =  sp*ct;   // u00
        const float v1r = -cm*st, v1i =  sm*st;   // u01
        const float v2r =  cm*st, v2i =  sm*st;   // u10
        const float v3r =  cp*ct, v3i = -sp*ct;   // u11
        rotu[w][0] = f32x2{v0r,v0r}; rotu[w][1] = f32x2{v0i,v0i};
        rotu[w][2] = f32x2{v1r,v1r}; rotu[w][3] = f32x2{v1i,v1i};
        rotu[w][4] = f32x2{v2r,v2r}; rotu[w][5] = f32x2{v2i,v2i};
        rotu[w][6] = f32x2{v3r,v3r}; rotu[w][7] = f32x2{v3i,v3i};
        if (w >= 3 && w < 9) {
            f32x2* g0 = rotg[w-3][0];   // bit=0: a=u00, b=u01
            g0[0] = f32x2{v0r,v0r}; g0[1] = f32x2{v0i,v0i};
            g0[2] = f32x2{v1r,v1r}; g0[3] = f32x2{v1i,v1i};
            f32x2* g1 = rotg[w-3][1];   // bit=1: a=u11, b=u10
            g1[0] = f32x2{v3r,v3r}; g1[1] = f32x2{v3i,v3i};
            g1[2] = f32x2{v2r,v2r}; g1[3] = f32x2{v2i,v2i};
        }
    } else if (wid == 1 && lane < 12) {
        // v_w = Rot^0_w * RY(x_w)|0>  (layer-0 product factor table) — parallel wave
        const int w = lane;
        const float phi   = var[w*3+0];
        const float theta = var[w*3+1];
        const float omega = var[w*3+2];
        float st, ct; sincosf(0.5f*theta, &st, &ct);
        float sp, cp; sincosf(-0.5f*(phi+omega), &sp, &cp);
        float sm, cm; sincosf(-0.5f*(phi-omega), &sm, &cm);
        float s_, c_; sincosf(0.5f * x[b*NW + w], &s_, &c_);
        const float v0r = cp*ct*c_ - cm*st*s_;
        const float v0i = sp*ct*c_ + sm*st*s_;
        const float v1r = cm*st*c_ + cp*ct*s_;
        const float v1i = sm*st*c_ - sp*ct*s_;
        fac[w*2+0][0] = v0r; fac[w*2+0][1] = v0r; fac[w*2+0][2] = v0i; fac[w*2+0][3] = v0i;
        fac[w*2+1][0] = v1r; fac[w*2+1][1] = v1r; fac[w*2+1][2] = v1i; fac[w*2+1][3] = v1i;
    }
    __syncthreads();

    St s;
    if (fast_ok) circuit<true >(s, ex, rotu, rotg, fac, t, lane, wid, bp32);
    else         circuit<false>(s, ex, rotu, rotg, fac, t, lane, wid, bp32);

    // ---- epilogue: probs -> z(M2 x) -> head (ring r=2 fused; validated R10/R11) ----
    // L0: x0=W2 x1=W1 x2=W0 | x3..x8 = l5..l0 | x9=j2 x10=j1 x11=j0
    float h[NW];
    #pragma unroll
    for (int w = 0; w < NW; ++w) h[w] = hw[w];
    const int W = wid, l = lane;
    const int s2 = ((W >> 2) ^ W) & 1;
    const int s3 = ((W >> 1) ^ (l >> 5)) & 1;
    const int s4 = s2 ^ ((l >> 4) & 1);
    const int s5 = s3 ^ ((l >> 3) & 1);
    const int s6 = s4 ^ ((l >> 2) & 1);
    const int s7 = s5 ^ ((l >> 1) & 1);
    const int s8 = s6 ^ (l & 1);
    const int c0 = (W ^ (l >> 4) ^ (l >> 2) ^ l) & 1;
    const int c10 = c0 ^ ((W >> 2) & 1);
    const int c9 = ((W >> 1) ^ (l >> 5) ^ (l >> 3) ^ (l >> 1)) & 1;
    const int c1 = c9 ^ ((W >> 1) & 1);

    const float base =
        (s2 ? -h[2] : h[2]) + (s3 ? -h[3] : h[3]) + (s4 ? -h[4] : h[4]) +
        (s5 ? -h[5] : h[5]) + (s6 ? -h[6] : h[6]) + (s7 ? -h[7] : h[7]) +
        (s8 ? -h[8] : h[8]);
    const float A  = (c0 ? -h[0] : h[0]) + (c10 ? -h[10] : h[10]);   // * (-1)^j1
    const float B  = (c1 ? -h[1] : h[1]) + (c9  ? -h[11] : h[11]);   // * (-1)^(j2^j0)
    const float Cc = (c9 ? -h[9] : h[9]);                            // * (-1)^j2

    float acc = 0.0f;
    #pragma unroll
    for (int j = 0; j < NA; ++j) {
        const float pr = s.z[j].x*s.z[j].x + s.z[j].y*s.z[j].y;
        float zz = base;
        zz += (j & 2) ? -A : A;
        zz += (j & 4) ? -Cc : Cc;
        zz += (((j >> 2) ^ j) & 1) ? -B : B;
        acc += pr * zz;
    }
    #pragma unroll
    for (int off = 32; off > 0; off >>= 1) acc += __shfl_down(acc, off, 64);
    if (lane == 0) wavesum[wid] = acc;
    __syncthreads();
    if (t == 0) {
        float r = hb[0];
        #pragma unroll
        for (int wv = 0; wv < 8; ++wv) r += wavesum[wv];
        out[b] = r;
    }
}

extern "C" void kernel_launch(void* const* d_in, const int* in_sizes, int n_in,
                              void* d_out, int out_size, void* d_ws, size_t ws_size,
                              hipStream_t stream) {
    const float* x   = (const float*)d_in[0];
    const float* var = (const float*)d_in[1];
    const float* hw  = (const float*)d_in[2];
    const float* hb  = (const float*)d_in[3];
    float* out = (float*)d_out;
    qnn_kernel<<<out_size, BT, 0, stream>>>(x, var, hw, hb, out);
}

// Round 17
// 9.986 us; speedup vs baseline: 1.7343x; 1.3141x over previous
//
#include <hip/hip_runtime.h>

constexpr int NSTR = 2664;   // sum over wires of 3^|S_w|, S_w = support of R2-pulled Z_w

struct TabT { unsigned ty[NSTR]; unsigned me[NSTR]; };
struct SlT  { int len[12]; int list[12][6]; };

// R2 = CNOT(w,(w+2)%12), w=0..11 in order. Pull Z_wp back: conjugate w=11..0,
// Z-only rule: z[ctrl] ^= z[tgt].
constexpr SlT build_s() {
    SlT s{};
    for (int wp = 0; wp < 12; ++wp) {
        unsigned z = 1u << wp;
        for (int w = 11; w >= 0; --w) {
            int c = w, tg = (w + 2) % 12;
            if ((z >> tg) & 1u) z ^= 1u << c;
        }
        int ns = 0;
        for (int k = 0; k < 12; ++k) if ((z >> k) & 1u) s.list[wp][ns++] = k;
        s.len[wp] = ns;
        for (int i = ns; i < 6; ++i) s.list[wp][i] = 12;   // pad -> qq[12][*]=1
    }
    return s;
}

// Expand each Z-string through U1 (choices X/Y/Z per support wire), then conjugate
// through R1 = CNOT(w,(w+1)%12) w=0..11 (conjugate w=11..0) with the CHP rule:
//   r ^= x_c z_t (x_t ^ z_c ^ 1);  x_t ^= x_c;  z_c ^= z_t.
constexpr TabT build_tab() {
    TabT t{};
    SlT s = build_s();
    int idx = 0;
    for (int wp = 0; wp < 12; ++wp) {
        int ns = s.len[wp];
        int total = 1;
        for (int i = 0; i < ns; ++i) total *= 3;
        for (int n = 0; n < total; ++n) {
            unsigned xm = 0, zm = 0, choices = 0; int sg = 0, nn = n;
            for (int i = 0; i < ns; ++i) {
                int d = nn % 3; nn /= 3;               // 0=X 1=Y 2=Z
                choices |= (unsigned)d << (2 * i);
                int k = s.list[wp][i];
                if (d == 0 || d == 1) xm |= 1u << k;
                if (d == 1 || d == 2) zm |= 1u << k;
            }
            for (int w = 11; w >= 0; --w) {
                int a = w, b2 = (w + 1) % 12;
                unsigned xa = (xm >> a) & 1u, zb = (zm >> b2) & 1u;
                unsigned xb = (xm >> b2) & 1u, za = (zm >> a) & 1u;
                sg ^= (int)(xa & zb & (xb ^ za ^ 1u));
                xm ^= xa << b2;
                zm ^= zb << a;
            }
            unsigned ty = 0;
            for (int k = 0; k < 12; ++k) {
                unsigned xx = (xm >> k) & 1u, zz = (zm >> k) & 1u;
                unsigned tp = (xx & zz) ? 2u : (xx ? 1u : (zz ? 3u : 0u));
                ty |= tp << (2 * k);
            }
            t.ty[idx] = ty;
            t.me[idx] = (unsigned)wp | ((unsigned)sg << 4) | (choices << 5);
            ++idx;
        }
    }
    return t;
}

__constant__ TabT g_tab = build_tab();
__constant__ SlT  g_sl  = build_s();

__global__ __launch_bounds__(512)
void qnn_kernel(const float* __restrict__ x, const float* __restrict__ var,
                const float* __restrict__ hw, const float* __restrict__ hb,
                float* __restrict__ out)
{
    __shared__ float mq[12][4];   // per-wire <v|P|v>, P in {I,X,Y,Z}; sample-dep
    __shared__ float qq[13][4];   // per-wire (.,a,b,c) of B = U1^dag Z U1; row 12 = 1-pad
    __shared__ float hh[12];
    __shared__ float wavesum[8];

    const int t = threadIdx.x, b = blockIdx.x;
    const int lane = t & 63, wid = t >> 6;

    if (wid == 0 && lane < 12) {
        // v = U0_w * RY(x_w)|0>   (factor formulas validated R11-R16)
        const int w = lane;
        const float phi = var[w*3+0], theta = var[w*3+1], omega = var[w*3+2];
        float st, ct; sincosf(0.5f*theta, &st, &ct);
        float sp, cp; sincosf(-0.5f*(phi+omega), &sp, &cp);
        float sm, cm; sincosf(-0.5f*(phi-omega), &sm, &cm);
        float s_, c_; sincosf(0.5f * x[b*12 + w], &s_, &c_);
        const float v0r = cp*ct*c_ - cm*st*s_;
        const float v0i = sp*ct*c_ + sm*st*s_;
        const float v1r = cm*st*c_ + cp*ct*s_;
        const float v1i = sm*st*c_ - sp*ct*s_;
        mq[w][0] = 1.0f;
        mq[w][1] = 2.0f*(v0r*v1r + v0i*v1i);            // <X>
        mq[w][2] = 2.0f*(v0r*v1i - v0i*v1r);            // <Y>
        mq[w][3] = (v0r*v0r + v0i*v0i) - (v1r*v1r + v1i*v1i);  // <Z>
        hh[w] = hw[w];
    } else if (wid == 1 && lane < 13) {
        if (lane < 12) {
            // B = U1^dag Z U1 = aX + bY + cZ (traceless Hermitian)
            const int w = lane, g = 12 + w;
            const float phi = var[g*3+0], theta = var[g*3+1], omega = var[g*3+2];
            float st, ct; sincosf(0.5f*theta, &st, &ct);
            float sp, cp; sincosf(-0.5f*(phi+omega), &sp, &cp);
            float sm, cm; sincosf(-0.5f*(phi-omega), &sm, &cm);
            const float u00r =  cp*ct, u00i =  sp*ct;
            const float u01r = -cm*st, u01i =  sm*st;
            const float u10r =  cm*st, u10i =  sm*st;
            const float u11r =  cp*ct, u11i = -sp*ct;
            const float B01r = (u00r*u01r + u00i*u01i) - (u10r*u11r + u10i*u11i);
            const float B01i = (u00r*u01i - u00i*u01r) - (u10r*u11i - u10i*u11r);
            qq[w][0] = 1.0f;
            qq[w][1] = B01r;                                         // a (X)
            qq[w][2] = -B01i;                                        // b (Y)
            qq[w][3] = (u00r*u00r + u00i*u00i) - (u10r*u10r + u10i*u10i);  // c (Z)
        } else {
            qq[12][0] = qq[12][1] = qq[12][2] = qq[12][3] = 1.0f;    // pad row
        }
    }
    __syncthreads();

    // E = hb + sum_strings (+-) h[wp] * (prod q over S choices) * (prod m over final types)
    float acc = 0.0f;
    for (int i = t; i < NSTR; i += 512) {
        const unsigned ty = g_tab.ty[i];
        const unsigned me = g_tab.me[i];
        const int wp = me & 15;
        const unsigned ch = me >> 5;
        float cf = hh[wp];
        #pragma unroll
        for (int ii = 0; ii < 6; ++ii) {
            const int k = g_sl.list[wp][ii];     // pads to 12 -> qq[12][*] = 1
            const int d = (ch >> (2*ii)) & 3;
            cf *= qq[k][d + 1];
        }
        if ((me >> 4) & 1) cf = -cf;
        #pragma unroll
        for (int k = 0; k < 12; ++k)
            cf *= mq[k][(ty >> (2*k)) & 3];      // type 0 = I -> *1
        acc += cf;
    }

    #pragma unroll
    for (int off = 32; off > 0; off >>= 1) acc += __shfl_down(acc, off, 64);
    if (lane == 0) wavesum[wid] = acc;
    __syncthreads();
    if (t == 0) {
        float r = hb[0];
        #pragma unroll
        for (int wv = 0; wv < 8; ++wv) r += wavesum[wv];
        out[b] = r;
    }
}

extern "C" void kernel_launch(void* const* d_in, const int* in_sizes, int n_in,
                              void* d_out, int out_size, void* d_ws, size_t ws_size,
                              hipStream_t stream) {
    const float* x   = (const float*)d_in[0];
    const float* var = (const float*)d_in[1];
    const float* hw  = (const float*)d_in[2];
    const float* hb  = (const float*)d_in[3];
    float* out = (float*)d_out;
    qnn_kernel<<<out_size, 512, 0, stream>>>(x, var, hw, hb, out);
}